// Round 4
// baseline (655.419 us; speedup 1.0000x reference)
//
#include <hip/hip_runtime.h>
#include <stdint.h>

// PackBits: out[w] = packed sign bits of x[32w .. 32w+31].
// Bit mapping (np.packbits MSB-first + little-endian uint32 view):
//   element p -> bit q = 8*(p>>3) + 7 - (p&7)
// Natural-order word nat (bit p = signbit(x[32w+p])), then
//   out = bswap(brev(nat))   — verified correct (absmax 0) in all rounds.
//
// R6: ballot-based packing. __ballot((int)x < 0) IS the 64-float packed sign
// mask in exact lane order — one v_cmp replaces the nibble pack + 3-step
// ds_swizzle butterfly of R2/R5 (24 LDS-pipe swizzles per wave-8KiB, each
// with lgkmcnt latency) and the 1/8-exec-masked 32 B stores.
// Layout: lane i loads float (seg + i), 4 dword loads per 1 KiB round (each
// instruction = 256 B contiguous, per-instruction coalesced). Wave covers a
// contiguous 8 KiB over 8 rounds -> 64 output words, exactly one per lane:
//   lane L's word = half (L&1) of ballot k=(L>>1)&3 on round j=L>>3,
// captured via uniform selects, then ONE fully-coalesced 256 B store/wave.
// Grid: 16384 blocks x 256 thr (32 KiB/block) — same shape as R5, which
// showed launch/locality is not the limiter; this round targets the
// swizzle + masked-store structure instead.

typedef uint32_t u32;
typedef unsigned long long u64;

#define THREADS 256
#define ROUNDS  8
#define WAVE_FLOATS  (ROUNDS * 256)      // 2048 floats per wave (8 KiB)
#define BLOCK_FLOATS (4 * WAVE_FLOATS)   // 8192 floats per block (32 KiB)

__global__ __launch_bounds__(THREADS) void PackBits_61289183314094_kernel(
    const int* __restrict__ x, u32* __restrict__ out, int n) {
  const int wave = threadIdx.x >> 6;
  const int lane = threadIdx.x & 63;
  const int fbase = blockIdx.x * BLOCK_FLOATS + wave * WAVE_FLOATS;  // wave-uniform

  if (fbase + WAVE_FLOATS <= n) {
    const int* p = x + fbase + lane;
    int v[ROUNDS][4];
#pragma unroll
    for (int j = 0; j < ROUNDS; ++j)
#pragma unroll
      for (int k = 0; k < 4; ++k)
        v[j][k] = __builtin_nontemporal_load(&p[j * 256 + k * 64]);

    u32 w = 0;
#pragma unroll
    for (int j = 0; j < ROUNDS; ++j) {
      // bit i of mk = signbit(x[fbase + j*256 + k*64 + i])
      u64 m0 = __ballot(v[j][0] < 0);
      u64 m1 = __ballot(v[j][1] < 0);
      u64 m2 = __ballot(v[j][2] < 0);
      u64 m3 = __ballot(v[j][3] < 0);
      // lane L owns bits [32L, 32L+32) of the wave's 2048-bit sign stream:
      // round j = L>>3, mask k = (L>>1)&3, half h = L&1.
      u64 ma = ((lane >> 1) & 1) ? m1 : m0;
      u64 mb = ((lane >> 1) & 1) ? m3 : m2;
      u64 m  = ((lane >> 2) & 1) ? mb : ma;
      u32 nat = (lane & 1) ? (u32)(m >> 32) : (u32)m;
      if ((lane >> 3) == j) w = __builtin_bswap32(__brev(nat));
    }
    // one coalesced 256 B store per wave
    __builtin_nontemporal_store(w, &out[(fbase >> 5) + lane]);
  } else {
    // Tail (unused for N = 2^27; kept general). Branch is wave-uniform, so
    // all 64 lanes participate in every ballot. Reference zero-pads, and
    // signbit(0) = 0, so OOB lanes contribute 0 bits.
    const int nwords = (n + 31) >> 5;
    u32 w = 0;
#pragma unroll
    for (int j = 0; j < ROUNDS; ++j) {
      u64 m0 = 0, m1 = 0, m2 = 0, m3 = 0;
      {
        int i0 = fbase + j * 256 + 0 * 64 + lane;
        int i1 = fbase + j * 256 + 1 * 64 + lane;
        int i2 = fbase + j * 256 + 2 * 64 + lane;
        int i3 = fbase + j * 256 + 3 * 64 + lane;
        int v0 = (i0 < n) ? x[i0] : 0;
        int v1 = (i1 < n) ? x[i1] : 0;
        int v2 = (i2 < n) ? x[i2] : 0;
        int v3 = (i3 < n) ? x[i3] : 0;
        m0 = __ballot(v0 < 0);
        m1 = __ballot(v1 < 0);
        m2 = __ballot(v2 < 0);
        m3 = __ballot(v3 < 0);
      }
      u64 ma = ((lane >> 1) & 1) ? m1 : m0;
      u64 mb = ((lane >> 1) & 1) ? m3 : m2;
      u64 m  = ((lane >> 2) & 1) ? mb : ma;
      u32 nat = (lane & 1) ? (u32)(m >> 32) : (u32)m;
      if ((lane >> 3) == j) w = __builtin_bswap32(__brev(nat));
    }
    int wi = (fbase >> 5) + lane;
    if (wi < nwords) out[wi] = w;
  }
}

extern "C" void kernel_launch(void* const* d_in, const int* in_sizes, int n_in,
                              void* d_out, int out_size, void* d_ws, size_t ws_size,
                              hipStream_t stream) {
  const int* x = (const int*)d_in[0];   // float bits; sign bit = (int < 0)
  u32* out = (u32*)d_out;
  int n = in_sizes[0];  // 2^27 floats

  int blocks = (n + BLOCK_FLOATS - 1) / BLOCK_FLOATS;  // 16384 for N = 2^27
  PackBits_61289183314094_kernel<<<blocks, THREADS, 0, stream>>>(x, out, n);
}